// Round 8
// baseline (574.385 us; speedup 1.0000x reference)
//
#include <hip/hip_runtime.h>
#include <hip/hip_bf16.h>

#define N_PTS (4096 * 192)
#define STRIDE 136     // bf16 elems per LDS act row
#define TM 128         // points per block (4 waves x 32 pts, wave-private rows)
#define PB_STRIDE 24   // posb row stride

typedef __bf16 bf16x8 __attribute__((ext_vector_type(8)));
typedef __bf16 bf16x4 __attribute__((ext_vector_type(4)));
typedef float  f32x4  __attribute__((ext_vector_type(4)));
typedef float  f32x2  __attribute__((ext_vector_type(2)));

// ws layout (bf16 element offsets), weight tiles transposed to [n][k]:
#define W1T 0          // 128x128
#define W2T 16384      // 128x128 (rows 0..127 of w2)
#define W3T 32768      // 128x128
#define WFT 49152      // 128x128
#define WRT 65536      // 64x128
#define W0E 73728      // 128x16  fixup: k0-2 w0_hi, k3-5 w0_hi(dup), k6-8 w0_lo
#define W2E 75776      // 128x16  same from w2 rows 128-130
#define WRE 77824      // 64x16   fixup: k9-14 wr vdir rows
#define WDT 78848      // 16x128  (unused; layout stability)
#define WSF 80896      // float region: woT[3][64]

__global__ void prep_kernel(const float* __restrict__ w0, const float* __restrict__ w1,
                            const float* __restrict__ w2, const float* __restrict__ w3,
                            const float* __restrict__ wf, const float* __restrict__ wr,
                            const float* __restrict__ wd, const float* __restrict__ wo,
                            __bf16* __restrict__ ws) {
  int i = blockIdx.x * 256 + threadIdx.x;
  if (i < 16384) { int n = i >> 7, k = i & 127; ws[i] = (__bf16)w1[k * 128 + n]; }
  else if (i < 32768) { int j = i - 16384, n = j >> 7, k = j & 127; ws[i] = (__bf16)w2[k * 128 + n]; }
  else if (i < 49152) { int j = i - 32768, n = j >> 7, k = j & 127; ws[i] = (__bf16)w3[k * 128 + n]; }
  else if (i < 65536) { int j = i - 49152, n = j >> 7, k = j & 127; ws[i] = (__bf16)wf[k * 128 + n]; }
  else if (i < 73728) { int j = i - 65536, n = j >> 7, k = j & 127; ws[i] = (__bf16)wr[k * 64 + n]; }
  else if (i < 75776) {
    int j = i - 73728, f = j >> 4, k = j & 15; float v = 0.f;
    if (k < 3)      v = w0[k * 128 + f];
    else if (k < 6) v = w0[(k - 3) * 128 + f];
    else if (k < 9) { float w = w0[(k - 6) * 128 + f]; v = w - (float)(__bf16)w; }
    ws[i] = (__bf16)v;
  }
  else if (i < 77824) {
    int j = i - 75776, f = j >> 4, k = j & 15; float v = 0.f;
    if (k < 3)      v = w2[(128 + k) * 128 + f];
    else if (k < 6) v = w2[(128 + k - 3) * 128 + f];
    else if (k < 9) { float w = w2[(128 + k - 6) * 128 + f]; v = w - (float)(__bf16)w; }
    ws[i] = (__bf16)v;
  }
  else if (i < 78848) {
    int j = i - 77824, n = j >> 4, k = j & 15; float v = 0.f;
    if (k >= 9 && k < 15) v = wr[(128 + ((k - 9) % 3)) * 64 + n];
    ws[i] = (__bf16)v;
  }
  else if (i < 80896) {
    int j = i - 78848, n = j >> 7, k = j & 127; float v = 0.f;
    if (n == 0) v = wd[k];
    ws[i] = (__bf16)v;
  }
  else if (i < 81088) {
    int g = i - 80896, c = g >> 6, kg = g & 63;
    float* wsf = (float*)(ws + WSF);
    wsf[g] = wo[kg * 3 + c];
  }
}

// Per-wave GEMM: acc[pt][ft] += W-tile (A: M=feats, FT*16 of them) x act (B: N=32 pts).
// actW = wave's private 32 rows. K=128.
template <int FT>
__device__ __forceinline__ void gemmP(const __bf16* __restrict__ actW,
                                      const __bf16* __restrict__ wT,
                                      f32x4 (&acc)[2][FT], int l16, int quad) {
#pragma unroll 2
  for (int kk = 0; kk < 4; ++kk) {
    bf16x8 a0 = *(const bf16x8*)(actW + l16 * STRIDE + kk * 32 + quad * 8);
    bf16x8 a1 = *(const bf16x8*)(actW + (16 + l16) * STRIDE + kk * 32 + quad * 8);
#pragma unroll
    for (int ft = 0; ft < FT; ++ft) {
      bf16x8 w = *(const bf16x8*)(wT + (size_t)(ft * 16 + l16) * 128 + kk * 32 + quad * 8);
      acc[0][ft] = __builtin_amdgcn_mfma_f32_16x16x32_bf16(w, a0, acc[0][ft], 0, 0, 0);
      acc[1][ft] = __builtin_amdgcn_mfma_f32_16x16x32_bf16(w, a1, acc[1][ft], 0, 0, 0);
    }
  }
}

// One K=32 MFMA block vs wave's posb rows (k0-15 meaningful; quads 2-3 feed zeros).
template <int FT>
__device__ __forceinline__ void gemmFixP(const __bf16* __restrict__ posbW,
                                         const __bf16* __restrict__ wext,
                                         f32x4 (&acc)[2][FT], int l16, int quad) {
  bf16x8 z;
#pragma unroll
  for (int i = 0; i < 8; ++i) z[i] = (__bf16)0.f;
  bf16x8 b0 = z, b1 = z;
  if (quad < 2) {
    b0 = *(const bf16x8*)(posbW + l16 * PB_STRIDE + quad * 8);
    b1 = *(const bf16x8*)(posbW + (16 + l16) * PB_STRIDE + quad * 8);
  }
#pragma unroll
  for (int ft = 0; ft < FT; ++ft) {
    bf16x8 w = z;
    if (quad < 2) w = *(const bf16x8*)(wext + (size_t)(ft * 16 + l16) * 16 + quad * 8);
    acc[0][ft] = __builtin_amdgcn_mfma_f32_16x16x32_bf16(w, b0, acc[0][ft], 0, 0, 0);
    acc[1][ft] = __builtin_amdgcn_mfma_f32_16x16x32_bf16(w, b1, acc[1][ft], 0, 0, 0);
  }
}

__device__ __forceinline__ void store_relu(f32x4 v, __bf16* dst) {
  bf16x4 p;
#pragma unroll
  for (int r = 0; r < 4; ++r) p[r] = (__bf16)fmaxf(v[r], 0.f);
  *(bf16x4*)dst = p;
}

// Write acc back to wave's private rows.
template <int FT>
__device__ __forceinline__ void epilogueP(f32x4 (&acc)[2][FT], __bf16* actW, int l16, int quad) {
#pragma unroll
  for (int ft = 0; ft < FT; ++ft) {
    store_relu(acc[0][ft], actW + l16 * STRIDE + ft * 16 + quad * 4);
    store_relu(acc[1][ft], actW + (16 + l16) * STRIDE + ft * 16 + quad * 4);
  }
}

template <int FT>
__device__ __forceinline__ void bias_initP(f32x4 (&acc)[2][FT], const float* __restrict__ b,
                                           int quad) {
#pragma unroll
  for (int ft = 0; ft < FT; ++ft) {
    f32x4 bv = *(const f32x4*)(b + ft * 16 + quad * 4);
    acc[0][ft] = bv;
    acc[1][ft] = bv;
  }
}

__global__ __launch_bounds__(256, 4) void nerf_kernel(
    const float* __restrict__ x,
    const float* __restrict__ b0, const float* __restrict__ b1,
    const float* __restrict__ b2, const float* __restrict__ b3,
    const float* __restrict__ wd, const float* __restrict__ bd,
    const float* __restrict__ bfv, const float* __restrict__ br,
    const float* __restrict__ bo,
    const __bf16* __restrict__ ws,
    float* __restrict__ out) {
  __shared__ __bf16 act[TM * STRIDE];        // 34,816 B
  __shared__ __bf16 posb[TM * PB_STRIDE];    //  6,144 B (total 40,960 -> 4 blocks/CU)

  const int tid  = threadIdx.x;
  const int wv   = tid >> 6;
  const int lane = tid & 63;
  const int quad = lane >> 4;
  const int l16  = lane & 15;
  const int p0   = blockIdx.x * TM;
  const int ptbase = wv * 32;               // wave's private point rows

  __bf16* actW  = act + ptbase * STRIDE;
  __bf16* posbW = posb + ptbase * PB_STRIDE;

  // ---- stage posb WAVE-LOCALLY (lanes 0-31 handle the wave's own 32 pts) ----
  // No __syncthreads anywhere: all act/posb rows are wave-private; in-wave
  // ds ordering is enforced by compiler-emitted lgkmcnt waits.
  if (lane < 32) {
    const float* xp = x + (size_t)(p0 + ptbase + lane) * 6;
    f32x2 a = *(const f32x2*)xp;
    f32x2 b = *(const f32x2*)(xp + 2);
    f32x2 c = *(const f32x2*)(xp + 4);
    float px = a[0], py = a[1], pz = b[0], vx = b[1], vy = c[0], vz = c[1];
    __bf16 phx = (__bf16)px, phy = (__bf16)py, phz = (__bf16)pz;
    __bf16 vhx = (__bf16)vx, vhy = (__bf16)vy, vhz = (__bf16)vz;
    __bf16 plx = (__bf16)(px - (float)phx), ply = (__bf16)(py - (float)phy), plz = (__bf16)(pz - (float)phz);
    __bf16 vlx = (__bf16)(vx - (float)vhx), vly = (__bf16)(vy - (float)vhy), vlz = (__bf16)(vz - (float)vhz);
    bf16x8 r0, r1;
    r0[0] = phx; r0[1] = phy; r0[2] = phz; r0[3] = plx; r0[4] = ply; r0[5] = plz; r0[6] = phx; r0[7] = phy;
    r1[0] = phz; r1[1] = vhx; r1[2] = vhy; r1[3] = vhz; r1[4] = vlx; r1[5] = vly; r1[6] = vlz; r1[7] = (__bf16)0.f;
    *(bf16x8*)(posbW + lane * PB_STRIDE) = r0;
    *(bf16x8*)(posbW + lane * PB_STRIDE + 8) = r1;
  }

  // ---- layer 0: h0 = relu(pos @ w0 + b0), all 128 feats for wave's 32 pts ----
  {
    f32x4 acc[2][8];
    bias_initP<8>(acc, b0, quad);
    gemmFixP<8>(posbW, ws + W0E, acc, l16, quad);
    epilogueP<8>(acc, actW, l16, quad);
  }

  // ---- layer 1 ----
  {
    f32x4 acc[2][8];
    bias_initP<8>(acc, b1, quad);
    gemmP<8>(actW, ws + W1T, acc, l16, quad);
    epilogueP<8>(acc, actW, l16, quad);
  }

  // ---- layer 2: + pos concat via fixup-MFMA ----
  {
    f32x4 acc[2][8];
    bias_initP<8>(acc, b2, quad);
    gemmP<8>(actW, ws + W2T, acc, l16, quad);
    gemmFixP<8>(posbW, ws + W2E, acc, l16, quad);
    epilogueP<8>(acc, actW, l16, quad);
  }

  // ---- layer 3 ----
  {
    f32x4 acc[2][8];
    bias_initP<8>(acc, b3, quad);
    gemmP<8>(actW, ws + W3T, acc, l16, quad);
    epilogueP<8>(acc, actW, l16, quad);
  }

  // ---- density = relu(h3 @ wd + bd): wave-local VALU dot (fp32 wd) ----
  {
    int pl = ptbase + (lane >> 1), half = lane & 1;
    const __bf16* hrow = act + pl * STRIDE + half * 64;
    const float*  wdp  = wd + half * 64;
    float s = 0.f;
#pragma unroll 2
    for (int c = 0; c < 8; ++c) {
      bf16x8 h = *(const bf16x8*)(hrow + c * 8);
      f32x4 wa = *(const f32x4*)(wdp + c * 8);
      f32x4 wb = *(const f32x4*)(wdp + c * 8 + 4);
      s += (float)h[0] * wa[0] + (float)h[1] * wa[1] + (float)h[2] * wa[2] + (float)h[3] * wa[3];
      s += (float)h[4] * wb[0] + (float)h[5] * wb[1] + (float)h[6] * wb[2] + (float)h[7] * wb[3];
    }
    s += __shfl_xor(s, 1, 64);
    if (half == 0) out[(size_t)3 * N_PTS + p0 + pl] = fmaxf(s + bd[0], 0.f);
  }

  // ---- features = relu(h3 @ wf + bf) ----
  {
    f32x4 acc[2][8];
    bias_initP<8>(acc, bfv, quad);
    gemmP<8>(actW, ws + WFT, acc, l16, quad);
    epilogueP<8>(acc, actW, l16, quad);
  }

  // ---- r = relu([features, vdir] @ wr + br): 64 feats ----
  {
    f32x4 acc[2][4];
    bias_initP<4>(acc, br, quad);
    gemmP<4>(actW, ws + WRT, acc, l16, quad);
    gemmFixP<4>(posbW, ws + WRE, acc, l16, quad);
    epilogueP<4>(acc, actW, l16, quad);
  }

  // ---- rgb = sigmoid(r @ wo + bo): wave-local ----
  {
    const float* woT = (const float*)(ws + WSF);  // [3][64]
    int pl = ptbase + (lane >> 1), half = lane & 1;
    const __bf16* rrow = act + pl * STRIDE + half * 32;
    float s0 = 0.f, s1 = 0.f, s2 = 0.f;
#pragma unroll 1
    for (int c = 0; c < 4; ++c) {
      bf16x8 h = *(const bf16x8*)(rrow + c * 8);
#pragma unroll
      for (int j = 0; j < 8; ++j) {
        int kg = half * 32 + c * 8 + j;
        float rv = (float)h[j];
        s0 += rv * woT[kg];
        s1 += rv * woT[64 + kg];
        s2 += rv * woT[128 + kg];
      }
    }
    s0 += __shfl_xor(s0, 1, 64);
    s1 += __shfl_xor(s1, 1, 64);
    s2 += __shfl_xor(s2, 1, 64);
    if (half == 0) {
      size_t o = (size_t)(p0 + pl) * 3;
      out[o + 0] = 1.f / (1.f + __expf(-(s0 + bo[0])));
      out[o + 1] = 1.f / (1.f + __expf(-(s1 + bo[1])));
      out[o + 2] = 1.f / (1.f + __expf(-(s2 + bo[2])));
    }
  }
}

extern "C" void kernel_launch(void* const* d_in, const int* in_sizes, int n_in,
                              void* d_out, int out_size, void* d_ws, size_t ws_size,
                              hipStream_t stream) {
  const float* x  = (const float*)d_in[0];
  const float* w0 = (const float*)d_in[1];
  const float* b0 = (const float*)d_in[2];
  const float* w1 = (const float*)d_in[3];
  const float* b1 = (const float*)d_in[4];
  const float* w2 = (const float*)d_in[5];
  const float* b2 = (const float*)d_in[6];
  const float* w3 = (const float*)d_in[7];
  const float* b3 = (const float*)d_in[8];
  const float* wd = (const float*)d_in[9];
  const float* bd = (const float*)d_in[10];
  const float* wf = (const float*)d_in[11];
  const float* bfv= (const float*)d_in[12];
  const float* wr = (const float*)d_in[13];
  const float* br = (const float*)d_in[14];
  const float* wo = (const float*)d_in[15];
  const float* bo = (const float*)d_in[16];
  __bf16* ws = (__bf16*)d_ws;
  float* out = (float*)d_out;

  prep_kernel<<<317, 256, 0, stream>>>(w0, w1, w2, w3, wf, wr, wd, wo, ws);
  nerf_kernel<<<N_PTS / TM, 256, 0, stream>>>(x, b0, b1, b2, b3, wd, bd, bfv, br, bo, ws, out);
}